// Round 6
// baseline (71.906 us; speedup 1.0000x reference)
//
#include <hip/hip_runtime.h>
#include <math.h>

// Beamline: D(0.45) [Q_c D(0.9)]x19 Q_19 D(0.45). Output = hypot(std(x)-s, std(y)-s).
// Only final x,y matter -> final px,py, z-channel, n_slices all dead.
//   x_f = m11(pz)*x0 + m12(pz)*px0  (exact chromatic linear map, deg-7 poly in pz)
//       + cubic(x0,px0,y0,py0)      (first-order drift-nonlinearity kicks, pz=0)
// Round-6: separate prep kernel again (round-5 fusion regressed: redundant
// per-block f64 prep + VGPR inflation killed occupancy), with cubic coeffs
// parallelized one-lane-per-drift. Finalize fused into beam via threadfence
// last-block pattern (acquire fence required: per-XCD L2 non-coherent) -> 2
// graph nodes. Per-block float4 partials, no contended atomics (round-2 lesson).
// No dynamic-index arrays anywhere hot (round-3 scratch lesson).

#define SIGMA_T 0.005
#define PZ_A 6.5e-3
#define NNODE 8
#define MAXQ 63
#define MAXBLK 2048

// cos(pi*(2i+1)/16), i = 0..7
#define T0  0.9807852804032304
#define T1  0.8314696123025452
#define T2  0.5555702330196022
#define T3  0.1950903220161283
#define T4 (-0.1950903220161283)
#define T5 (-0.5555702330196022)
#define T6 (-0.8314696123025452)
#define T7 (-0.9807852804032304)

struct M2 { double a11, a12, a21, a22; };

// quad 2x2 via signed-u series: u = A*L^2, C=sum u^k/(2k)!, S=sum u^k/(2k+1)!
// cos/cosh and sin/sinh unify; matches Bmad quad_mat2_calc to ~1e-17 for |u|<=0.05.
__device__ inline M2 quadmatS(double A, double rp, double irp, double L) {
    double u = A * L * L;
    double C = fma(u, fma(u, fma(u, fma(u, fma(u, fma(u, 1.0/479001600.0, 1.0/3628800.0),
                    1.0/40320.0), 1.0/720.0), 1.0/24.0), 0.5), 1.0);
    double S = fma(u, fma(u, fma(u, fma(u, fma(u, fma(u, 1.0/6227020800.0, 1.0/39916800.0),
                    1.0/362880.0), 1.0/5040.0), 1.0/120.0), 1.0/6.0), 1.0);
    M2 m;
    double LS = L * S;
    m.a11 = C;
    m.a12 = LS * irp;
    m.a21 = A * LS * rp;
    m.a22 = C;
    return m;
}
__device__ inline void lmul(M2& M, const M2& E) {  // M <- E*M
    double n11 = E.a11*M.a11 + E.a12*M.a21;
    double n12 = E.a11*M.a12 + E.a12*M.a22;
    double n21 = E.a21*M.a11 + E.a22*M.a21;
    double n22 = E.a21*M.a12 + E.a22*M.a22;
    M.a11=n11; M.a12=n12; M.a21=n21; M.a22=n22;
}
__device__ inline void ldrift(M2& M, double d) {   // M <- [[1,d],[0,1]]*M
    M.a11 += d * M.a21;
    M.a12 += d * M.a22;
}

__device__ inline float uniflds(const float* p) {
    return __int_as_float(__builtin_amdgcn_readfirstlane(__float_as_int(*p)));
}

// cf layout (floats at d_ws+64):
//  [0..31]  horner: f*8+k, f in {mx11,mx12,my11,my12}, ascending power of t=pz/PZ_A
//  [32..41] Cx[10]: dx = x(C0 xx+C1 xp+C2 pp+C4 yy+C5 yq+C6 qq) + p(C3 pp+C7 yy+C8 yq+C9 qq)
//  [42..51] Cy[10]: symmetric
__global__ void prep_kernel(const float* __restrict__ ks, int Q,
                            float* __restrict__ cf, unsigned* __restrict__ counter)
{
    __shared__ double Mn[NNODE][4];
    __shared__ float klds[MAXQ + 1];
    const int tid  = threadIdx.x;
    const int lane = tid & 63;
    const int wid  = tid >> 6;
    if (Q > MAXQ) Q = MAXQ;

    if (tid == 0) *counter = 0u;          // reset last-block counter each launch
    if (tid < Q) klds[tid] = ks[tid];
    __syncthreads();

    if (wid == 0 && lane < NNODE) {
        // ---- Chebyshev node lattice (exact chromatic linear map), 8 lanes ----
        double t = (lane < 4) ? ((lane < 2) ? (lane == 0 ? T0 : T1)
                                            : (lane == 2 ? T2 : T3))
                              : ((lane < 6) ? (lane == 4 ? T4 : T5)
                                            : (lane == 6 ? T6 : T7));
        double pz = PZ_A * t;
        double rp = 1.0 + pz;
        double irp = 1.0 / rp;            // only runtime f64 division
        M2 X{1,0,0,1}, Y{1,0,0,1};
        ldrift(X, 0.45*irp); ldrift(Y, 0.45*irp);
        for (int c = 0; c < Q; ++c) {
            double k1n = (double)klds[c] * irp;
            lmul(X, quadmatS(-k1n, rp, irp, 0.1));
            lmul(Y, quadmatS( k1n, rp, irp, 0.1));
            double d = ((c == Q-1) ? 0.45 : 0.9) * irp;
            ldrift(X, d); ldrift(Y, d);
        }
        Mn[lane][0]=X.a11; Mn[lane][1]=X.a12; Mn[lane][2]=Y.a11; Mn[lane][3]=Y.a12;
    } else if (wid == 1) {
        // ---- cubic drift-kick coeffs at pz=0: one lane per drift j ----
        // Kick at end of drift j: du = L*pu*(pu^2+pv^2)/2, pu = a*x0+b*px0 with
        // (a,b) = prefix (a21,a22) at drift-j start (drift preserves a21,a22),
        // propagated by R = Mtot.a11*b - Mtot.a12*a (det=1).
        double con[20];
        #pragma unroll
        for (int v = 0; v < 20; ++v) con[v] = 0.0;
        {
            M2 X{1,0,0,1}, Y{1,0,0,1};
            double a=0.0, b=1.0, c2=0.0, d2=1.0, Lj=0.45;
            for (int c = 0; c <= Q; ++c) {
                double L = (c == 0 || c == Q) ? 0.45 : 0.9;
                if (c == lane) { a=X.a21; b=X.a22; c2=Y.a21; d2=Y.a22; Lj=L; }
                ldrift(X, L); ldrift(Y, L);
                if (c < Q) {
                    double k1 = (double)klds[c];
                    lmul(X, quadmatS(-k1, 1.0, 1.0, 0.1));
                    lmul(Y, quadmatS( k1, 1.0, 1.0, 0.1));
                }
            }
            if (lane <= Q) {
                double Rx = X.a11*b - X.a12*a;
                double Ry = Y.a11*d2 - Y.a12*c2;
                double g = 0.5 * Lj * Rx;
                double h = 0.5 * Lj * Ry;
                con[0]=g*a*a*a;   con[1]=3.0*g*a*a*b;  con[2]=3.0*g*a*b*b;  con[3]=g*b*b*b;
                con[4]=g*a*c2*c2; con[5]=2.0*g*a*c2*d2; con[6]=g*a*d2*d2;
                con[7]=g*b*c2*c2; con[8]=2.0*g*b*c2*d2; con[9]=g*b*d2*d2;
                con[10]=h*c2*c2*c2; con[11]=3.0*h*c2*c2*d2; con[12]=3.0*h*c2*d2*d2; con[13]=h*d2*d2*d2;
                con[14]=h*c2*a*a;  con[15]=2.0*h*c2*a*b; con[16]=h*c2*b*b;
                con[17]=h*d2*a*a;  con[18]=2.0*h*d2*a*b; con[19]=h*d2*b*b;
            }
        }
        #pragma unroll
        for (int v = 0; v < 20; ++v) {
            #pragma unroll
            for (int off = 32; off > 0; off >>= 1)
                con[v] += __shfl_down(con[v], off, 64);
        }
        if (lane == 0) {
            #pragma unroll
            for (int v = 0; v < 10; ++v) { cf[32+v]=(float)con[v]; cf[42+v]=(float)con[10+v]; }
        }
    }
    __syncthreads();

    if (tid < 4) {
        // Newton divided differences, fully unrolled (registers only).
        // Constant divisors written as reciprocal multiplies.
        constexpr double TN[NNODE] = {T0, T1, T2, T3, T4, T5, T6, T7};
        double d[NNODE];
        #pragma unroll
        for (int m = 0; m < NNODE; ++m) d[m] = Mn[m][tid];
        #pragma unroll
        for (int k = 1; k < NNODE; ++k) {
            #pragma unroll
            for (int m = NNODE - 1; m >= 1; --m) {
                if (m >= k) d[m] = (d[m] - d[m-1]) * (1.0 / (TN[m] - TN[m-k]));
            }
        }
        double c[NNODE];
        c[0] = d[NNODE-1];
        #pragma unroll
        for (int k = 1; k < NNODE; ++k) c[k] = 0.0;
        #pragma unroll
        for (int m = NNODE - 2; m >= 0; --m) {
            #pragma unroll
            for (int k = NNODE - 1; k >= 1; --k) c[k] = c[k-1] - TN[m]*c[k];
            c[0] = d[m] - TN[m]*c[0];
        }
        #pragma unroll
        for (int k = 0; k < NNODE; ++k) cf[tid*8 + k] = (float)c[k];
    }
}

__global__ __launch_bounds__(256) void beam_kernel(
    const float* __restrict__ xs, const float* __restrict__ pxs,
    const float* __restrict__ ys, const float* __restrict__ pys,
    const float* __restrict__ pzs, const float* __restrict__ cf,
    int n4, int ntail, float4* __restrict__ partials,
    unsigned* __restrict__ counter, float* __restrict__ out, int N)
{
    float h[32], Cx[10], Cy[10];
    #pragma unroll
    for (int k = 0; k < 32; ++k) h[k] = uniflds(cf + k);
    #pragma unroll
    for (int k = 0; k < 10; ++k) { Cx[k] = uniflds(cf + 32 + k); Cy[k] = uniflds(cf + 42 + k); }

    const float inva = (float)(1.0 / PZ_A);
    float s1x = 0.f, s2x = 0.f, s1y = 0.f, s2y = 0.f;

    auto track = [&](float x, float p, float y, float q, float pz) {
        float t = pz * inva;
        float m11 = h[7], m12 = h[15], n11 = h[23], n12 = h[31];
        #pragma unroll
        for (int k = 6; k >= 0; --k) {
            m11 = fmaf(m11, t, h[k]);
            m12 = fmaf(m12, t, h[8+k]);
            n11 = fmaf(n11, t, h[16+k]);
            n12 = fmaf(n12, t, h[24+k]);
        }
        float xx = x*x, xp = x*p, pp = p*p;
        float yy = y*y, yq = y*q, qq = q*q;
        float A1 = Cx[0]*xx; A1=fmaf(Cx[1],xp,A1); A1=fmaf(Cx[2],pp,A1);
        A1=fmaf(Cx[4],yy,A1); A1=fmaf(Cx[5],yq,A1); A1=fmaf(Cx[6],qq,A1);
        float A2 = Cx[3]*pp; A2=fmaf(Cx[7],yy,A2); A2=fmaf(Cx[8],yq,A2); A2=fmaf(Cx[9],qq,A2);
        float B1 = Cy[0]*yy; B1=fmaf(Cy[1],yq,B1); B1=fmaf(Cy[2],qq,B1);
        B1=fmaf(Cy[4],xx,B1); B1=fmaf(Cy[5],xp,B1); B1=fmaf(Cy[6],pp,B1);
        float B2 = Cy[3]*qq; B2=fmaf(Cy[7],xx,B2); B2=fmaf(Cy[8],xp,B2); B2=fmaf(Cy[9],pp,B2);
        float xf = fmaf(m11, x, m12*p); xf = fmaf(x, A1, xf); xf = fmaf(p, A2, xf);
        float yf = fmaf(n11, y, n12*q); yf = fmaf(y, B1, yf); yf = fmaf(q, B2, yf);
        s1x += xf; s2x = fmaf(xf, xf, s2x);
        s1y += yf; s2y = fmaf(yf, yf, s2y);
    };

    const int gstride = gridDim.x * blockDim.x;
    for (int i = blockIdx.x * blockDim.x + threadIdx.x; i < n4; i += gstride) {
        float4 xv  = ((const float4*)xs)[i];
        float4 pxv = ((const float4*)pxs)[i];
        float4 yv  = ((const float4*)ys)[i];
        float4 pyv = ((const float4*)pys)[i];
        float4 pzv = ((const float4*)pzs)[i];
        track(xv.x, pxv.x, yv.x, pyv.x, pzv.x);
        track(xv.y, pxv.y, yv.y, pyv.y, pzv.y);
        track(xv.z, pxv.z, yv.z, pyv.z, pzv.z);
        track(xv.w, pxv.w, yv.w, pyv.w, pzv.w);
    }
    if (blockIdx.x == 0 && threadIdx.x == 0) {
        for (int r = 0; r < ntail; ++r) {
            int idx = 4*n4 + r;
            track(xs[idx], pxs[idx], ys[idx], pys[idx], pzs[idx]);
        }
    }

    // wave shuffle reduce, then LDS across 4 waves
    for (int off = 32; off > 0; off >>= 1) {
        s1x += __shfl_down(s1x, off, 64);
        s2x += __shfl_down(s2x, off, 64);
        s1y += __shfl_down(s1y, off, 64);
        s2y += __shfl_down(s2y, off, 64);
    }
    __shared__ float red[4][4];
    const int lane = threadIdx.x & 63;
    const int wid  = threadIdx.x >> 6;
    if (lane == 0) {
        red[wid][0] = s1x; red[wid][1] = s2x;
        red[wid][2] = s1y; red[wid][3] = s2y;
    }
    __syncthreads();

    __shared__ bool amlast;
    if (threadIdx.x == 0) {
        float a = 0.f, b = 0.f, c = 0.f, d = 0.f;
        const int nw = (blockDim.x + 63) >> 6;
        for (int w = 0; w < nw; ++w) {
            a += red[w][0]; b += red[w][1];
            c += red[w][2]; d += red[w][3];
        }
        partials[blockIdx.x] = make_float4(a, b, c, d);
        __threadfence();                       // release: write back partials
        unsigned prev = atomicAdd(counter, 1u);
        amlast = (prev == gridDim.x - 1);
    }
    __syncthreads();
    if (!amlast) return;

    // ---- last block: fused finalize (deterministic fixed-order reduction) ----
    __threadfence();                           // acquire: per-XCD L2 not coherent
    double a = 0.0, b = 0.0, c = 0.0, d = 0.0;
    const int nparts = gridDim.x;
    for (int i = threadIdx.x; i < nparts; i += 256) {
        float4 p = partials[i];
        a += (double)p.x; b += (double)p.y;
        c += (double)p.z; d += (double)p.w;
    }
    for (int off = 32; off > 0; off >>= 1) {
        a += __shfl_down(a, off, 64);
        b += __shfl_down(b, off, 64);
        c += __shfl_down(c, off, 64);
        d += __shfl_down(d, off, 64);
    }
    __shared__ double dred[4][4];
    if (lane == 0) {
        dred[wid][0] = a; dred[wid][1] = b; dred[wid][2] = c; dred[wid][3] = d;
    }
    __syncthreads();
    if (threadIdx.x == 0) {
        double sa = 0, sb = 0, sc = 0, sd = 0;
        for (int w = 0; w < 4; ++w) {
            sa += dred[w][0]; sb += dred[w][1];
            sc += dred[w][2]; sd += dred[w][3];
        }
        const double n  = (double)N;
        const double vx = (sb - sa*sa/n) / (n - 1.0);
        const double vy = (sd - sc*sc/n) / (n - 1.0);
        const double dx = sqrt(vx) - SIGMA_T;
        const double dy = sqrt(vy) - SIGMA_T;
        out[0] = (float)sqrt(dx*dx + dy*dy);
    }
}

extern "C" void kernel_launch(void* const* d_in, const int* in_sizes, int n_in,
                              void* d_out, int out_size, void* d_ws, size_t ws_size,
                              hipStream_t stream) {
    const float* xs  = (const float*)d_in[0];
    const float* pxs = (const float*)d_in[1];
    const float* ys  = (const float*)d_in[2];
    const float* pys = (const float*)d_in[3];
    // d_in[4] = z : dead
    const float* pzs = (const float*)d_in[5];
    const float* ks  = (const float*)d_in[6];
    // d_in[7] = n_slices : dead (exact slice composition)

    const int N = in_sizes[0];
    const int Q = in_sizes[6];

    unsigned* counter  = (unsigned*)d_ws;
    float*    cf       = (float*)((char*)d_ws + 64);
    float4*   partials = (float4*)((char*)d_ws + 4096);

    prep_kernel<<<1, 128, 0, stream>>>(ks, Q, cf, counter);

    const int n4 = N >> 2;
    const int ntail = N & 3;
    int blocks = (n4 + 255) / 256;
    if (blocks < 1) blocks = 1;
    if (blocks > MAXBLK) blocks = MAXBLK;
    beam_kernel<<<blocks, 256, 0, stream>>>(
        xs, pxs, ys, pys, pzs, cf, n4, ntail, partials, counter, (float*)d_out, N);
}

// Round 7
// 24.708 us; speedup vs baseline: 2.9102x; 2.9102x over previous
//
#include <hip/hip_runtime.h>
#include <math.h>

// Beamline: D(0.45) [Q_c D(0.9)]x19 Q_19 D(0.45). Output = hypot(std(x)-s, std(y)-s).
// Only final x,y matter -> final px,py, z-channel, n_slices all dead.
//   x_f = m11(pz)*x0 + m12(pz)*px0  (exact chromatic linear map, deg-7 poly in pz)
//       + cubic(x0,px0,y0,py0)      (first-order drift-nonlinearity kicks, pz=0)
// Round-7 = round-4's proven 3-node structure (prep / beam / finalize) with the
// cubic prep parallelized one-lane-per-drift (round-6's prep, minus counter).
// Lessons kept: no contended atomics (R2: 100us floor), no dynamic-index arrays
// (R3: scratch), no per-block redundant prep (R5: occupancy loss), no per-block
// device-scope fences (R6: agent-release = L2 flush, +37us).

#define SIGMA_T 0.005
#define PZ_A 6.5e-3
#define NNODE 8
#define MAXQ 63
#define MAXBLK 2048

// cos(pi*(2i+1)/16), i = 0..7
#define T0  0.9807852804032304
#define T1  0.8314696123025452
#define T2  0.5555702330196022
#define T3  0.1950903220161283
#define T4 (-0.1950903220161283)
#define T5 (-0.5555702330196022)
#define T6 (-0.8314696123025452)
#define T7 (-0.9807852804032304)

struct M2 { double a11, a12, a21, a22; };

// quad 2x2 via signed-u series: u = A*L^2, C=sum u^k/(2k)!, S=sum u^k/(2k+1)!
// cos/cosh and sin/sinh unify; matches Bmad quad_mat2_calc to ~1e-17 for |u|<=0.05.
__device__ inline M2 quadmatS(double A, double rp, double irp, double L) {
    double u = A * L * L;
    double C = fma(u, fma(u, fma(u, fma(u, fma(u, fma(u, 1.0/479001600.0, 1.0/3628800.0),
                    1.0/40320.0), 1.0/720.0), 1.0/24.0), 0.5), 1.0);
    double S = fma(u, fma(u, fma(u, fma(u, fma(u, fma(u, 1.0/6227020800.0, 1.0/39916800.0),
                    1.0/362880.0), 1.0/5040.0), 1.0/120.0), 1.0/6.0), 1.0);
    M2 m;
    double LS = L * S;
    m.a11 = C;
    m.a12 = LS * irp;
    m.a21 = A * LS * rp;
    m.a22 = C;
    return m;
}
__device__ inline void lmul(M2& M, const M2& E) {  // M <- E*M
    double n11 = E.a11*M.a11 + E.a12*M.a21;
    double n12 = E.a11*M.a12 + E.a12*M.a22;
    double n21 = E.a21*M.a11 + E.a22*M.a21;
    double n22 = E.a21*M.a12 + E.a22*M.a22;
    M.a11=n11; M.a12=n12; M.a21=n21; M.a22=n22;
}
__device__ inline void ldrift(M2& M, double d) {   // M <- [[1,d],[0,1]]*M
    M.a11 += d * M.a21;
    M.a12 += d * M.a22;
}

__device__ inline float uniflds(const float* p) {
    return __int_as_float(__builtin_amdgcn_readfirstlane(__float_as_int(*p)));
}

// cf layout (floats at d_ws+64):
//  [0..31]  horner: f*8+k, f in {mx11,mx12,my11,my12}, ascending power of t=pz/PZ_A
//  [32..41] Cx[10]: dx = x(C0 xx+C1 xp+C2 pp+C4 yy+C5 yq+C6 qq) + p(C3 pp+C7 yy+C8 yq+C9 qq)
//  [42..51] Cy[10]: symmetric
__global__ void prep_kernel(const float* __restrict__ ks, int Q,
                            float* __restrict__ cf)
{
    __shared__ double Mn[NNODE][4];
    __shared__ float klds[MAXQ + 1];
    const int tid  = threadIdx.x;
    const int lane = tid & 63;
    const int wid  = tid >> 6;
    if (Q > MAXQ) Q = MAXQ;

    if (tid < Q) klds[tid] = ks[tid];
    __syncthreads();

    if (wid == 0 && lane < NNODE) {
        // ---- Chebyshev node lattice (exact chromatic linear map), 8 lanes ----
        double t = (lane < 4) ? ((lane < 2) ? (lane == 0 ? T0 : T1)
                                            : (lane == 2 ? T2 : T3))
                              : ((lane < 6) ? (lane == 4 ? T4 : T5)
                                            : (lane == 6 ? T6 : T7));
        double pz = PZ_A * t;
        double rp = 1.0 + pz;
        double irp = 1.0 / rp;            // only runtime f64 division
        M2 X{1,0,0,1}, Y{1,0,0,1};
        ldrift(X, 0.45*irp); ldrift(Y, 0.45*irp);
        for (int c = 0; c < Q; ++c) {
            double k1n = (double)klds[c] * irp;
            lmul(X, quadmatS(-k1n, rp, irp, 0.1));
            lmul(Y, quadmatS( k1n, rp, irp, 0.1));
            double d = ((c == Q-1) ? 0.45 : 0.9) * irp;
            ldrift(X, d); ldrift(Y, d);
        }
        Mn[lane][0]=X.a11; Mn[lane][1]=X.a12; Mn[lane][2]=Y.a11; Mn[lane][3]=Y.a12;
    } else if (wid == 1) {
        // ---- cubic drift-kick coeffs at pz=0: one lane per drift j ----
        // Kick at end of drift j: du = L*pu*(pu^2+pv^2)/2, pu = a*x0+b*px0 with
        // (a,b) = prefix (a21,a22) at drift-j start (drift preserves a21,a22),
        // propagated by R = Mtot.a11*b - Mtot.a12*a (det=1).
        double con[20];
        #pragma unroll
        for (int v = 0; v < 20; ++v) con[v] = 0.0;
        {
            M2 X{1,0,0,1}, Y{1,0,0,1};
            double a=0.0, b=1.0, c2=0.0, d2=1.0, Lj=0.45;
            for (int c = 0; c <= Q; ++c) {
                double L = (c == 0 || c == Q) ? 0.45 : 0.9;
                if (c == lane) { a=X.a21; b=X.a22; c2=Y.a21; d2=Y.a22; Lj=L; }
                ldrift(X, L); ldrift(Y, L);
                if (c < Q) {
                    double k1 = (double)klds[c];
                    lmul(X, quadmatS(-k1, 1.0, 1.0, 0.1));
                    lmul(Y, quadmatS( k1, 1.0, 1.0, 0.1));
                }
            }
            if (lane <= Q) {
                double Rx = X.a11*b - X.a12*a;
                double Ry = Y.a11*d2 - Y.a12*c2;
                double g = 0.5 * Lj * Rx;
                double h = 0.5 * Lj * Ry;
                con[0]=g*a*a*a;   con[1]=3.0*g*a*a*b;  con[2]=3.0*g*a*b*b;  con[3]=g*b*b*b;
                con[4]=g*a*c2*c2; con[5]=2.0*g*a*c2*d2; con[6]=g*a*d2*d2;
                con[7]=g*b*c2*c2; con[8]=2.0*g*b*c2*d2; con[9]=g*b*d2*d2;
                con[10]=h*c2*c2*c2; con[11]=3.0*h*c2*c2*d2; con[12]=3.0*h*c2*d2*d2; con[13]=h*d2*d2*d2;
                con[14]=h*c2*a*a;  con[15]=2.0*h*c2*a*b; con[16]=h*c2*b*b;
                con[17]=h*d2*a*a;  con[18]=2.0*h*d2*a*b; con[19]=h*d2*b*b;
            }
        }
        #pragma unroll
        for (int v = 0; v < 20; ++v) {
            #pragma unroll
            for (int off = 32; off > 0; off >>= 1)
                con[v] += __shfl_down(con[v], off, 64);
        }
        if (lane == 0) {
            #pragma unroll
            for (int v = 0; v < 10; ++v) { cf[32+v]=(float)con[v]; cf[42+v]=(float)con[10+v]; }
        }
    }
    __syncthreads();

    if (tid < 4) {
        // Newton divided differences, fully unrolled (registers only).
        // Constant divisors written as reciprocal multiplies.
        constexpr double TN[NNODE] = {T0, T1, T2, T3, T4, T5, T6, T7};
        double d[NNODE];
        #pragma unroll
        for (int m = 0; m < NNODE; ++m) d[m] = Mn[m][tid];
        #pragma unroll
        for (int k = 1; k < NNODE; ++k) {
            #pragma unroll
            for (int m = NNODE - 1; m >= 1; --m) {
                if (m >= k) d[m] = (d[m] - d[m-1]) * (1.0 / (TN[m] - TN[m-k]));
            }
        }
        double c[NNODE];
        c[0] = d[NNODE-1];
        #pragma unroll
        for (int k = 1; k < NNODE; ++k) c[k] = 0.0;
        #pragma unroll
        for (int m = NNODE - 2; m >= 0; --m) {
            #pragma unroll
            for (int k = NNODE - 1; k >= 1; --k) c[k] = c[k-1] - TN[m]*c[k];
            c[0] = d[m] - TN[m]*c[0];
        }
        #pragma unroll
        for (int k = 0; k < NNODE; ++k) cf[tid*8 + k] = (float)c[k];
    }
}

__global__ __launch_bounds__(256) void beam_kernel(
    const float* __restrict__ xs, const float* __restrict__ pxs,
    const float* __restrict__ ys, const float* __restrict__ pys,
    const float* __restrict__ pzs, const float* __restrict__ cf,
    int n4, int ntail, float4* __restrict__ partials)
{
    float h[32], Cx[10], Cy[10];
    #pragma unroll
    for (int k = 0; k < 32; ++k) h[k] = uniflds(cf + k);
    #pragma unroll
    for (int k = 0; k < 10; ++k) { Cx[k] = uniflds(cf + 32 + k); Cy[k] = uniflds(cf + 42 + k); }

    const float inva = (float)(1.0 / PZ_A);
    float s1x = 0.f, s2x = 0.f, s1y = 0.f, s2y = 0.f;

    auto track = [&](float x, float p, float y, float q, float pz) {
        float t = pz * inva;
        float m11 = h[7], m12 = h[15], n11 = h[23], n12 = h[31];
        #pragma unroll
        for (int k = 6; k >= 0; --k) {
            m11 = fmaf(m11, t, h[k]);
            m12 = fmaf(m12, t, h[8+k]);
            n11 = fmaf(n11, t, h[16+k]);
            n12 = fmaf(n12, t, h[24+k]);
        }
        float xx = x*x, xp = x*p, pp = p*p;
        float yy = y*y, yq = y*q, qq = q*q;
        float A1 = Cx[0]*xx; A1=fmaf(Cx[1],xp,A1); A1=fmaf(Cx[2],pp,A1);
        A1=fmaf(Cx[4],yy,A1); A1=fmaf(Cx[5],yq,A1); A1=fmaf(Cx[6],qq,A1);
        float A2 = Cx[3]*pp; A2=fmaf(Cx[7],yy,A2); A2=fmaf(Cx[8],yq,A2); A2=fmaf(Cx[9],qq,A2);
        float B1 = Cy[0]*yy; B1=fmaf(Cy[1],yq,B1); B1=fmaf(Cy[2],qq,B1);
        B1=fmaf(Cy[4],xx,B1); B1=fmaf(Cy[5],xp,B1); B1=fmaf(Cy[6],pp,B1);
        float B2 = Cy[3]*qq; B2=fmaf(Cy[7],xx,B2); B2=fmaf(Cy[8],xp,B2); B2=fmaf(Cy[9],pp,B2);
        float xf = fmaf(m11, x, m12*p); xf = fmaf(x, A1, xf); xf = fmaf(p, A2, xf);
        float yf = fmaf(n11, y, n12*q); yf = fmaf(y, B1, yf); yf = fmaf(q, B2, yf);
        s1x += xf; s2x = fmaf(xf, xf, s2x);
        s1y += yf; s2y = fmaf(yf, yf, s2y);
    };

    const int gstride = gridDim.x * blockDim.x;
    for (int i = blockIdx.x * blockDim.x + threadIdx.x; i < n4; i += gstride) {
        float4 xv  = ((const float4*)xs)[i];
        float4 pxv = ((const float4*)pxs)[i];
        float4 yv  = ((const float4*)ys)[i];
        float4 pyv = ((const float4*)pys)[i];
        float4 pzv = ((const float4*)pzs)[i];
        track(xv.x, pxv.x, yv.x, pyv.x, pzv.x);
        track(xv.y, pxv.y, yv.y, pyv.y, pzv.y);
        track(xv.z, pxv.z, yv.z, pyv.z, pzv.z);
        track(xv.w, pxv.w, yv.w, pyv.w, pzv.w);
    }
    if (blockIdx.x == 0 && threadIdx.x == 0) {
        for (int r = 0; r < ntail; ++r) {
            int idx = 4*n4 + r;
            track(xs[idx], pxs[idx], ys[idx], pys[idx], pzs[idx]);
        }
    }

    // wave shuffle reduce, then LDS across 4 waves
    for (int off = 32; off > 0; off >>= 1) {
        s1x += __shfl_down(s1x, off, 64);
        s2x += __shfl_down(s2x, off, 64);
        s1y += __shfl_down(s1y, off, 64);
        s2y += __shfl_down(s2y, off, 64);
    }
    __shared__ float red[4][4];
    const int lane = threadIdx.x & 63;
    const int wid  = threadIdx.x >> 6;
    if (lane == 0) {
        red[wid][0] = s1x; red[wid][1] = s2x;
        red[wid][2] = s1y; red[wid][3] = s2y;
    }
    __syncthreads();
    if (threadIdx.x == 0) {
        float a = 0.f, b = 0.f, c = 0.f, d = 0.f;
        const int nw = (blockDim.x + 63) >> 6;
        for (int w = 0; w < nw; ++w) {
            a += red[w][0]; b += red[w][1];
            c += red[w][2]; d += red[w][3];
        }
        partials[blockIdx.x] = make_float4(a, b, c, d);  // no atomics
    }
}

__global__ __launch_bounds__(256) void finalize_kernel(
    const float4* __restrict__ partials, int nparts,
    float* __restrict__ out, int N)
{
    double a = 0.0, b = 0.0, c = 0.0, d = 0.0;
    for (int i = threadIdx.x; i < nparts; i += 256) {
        float4 p = partials[i];
        a += (double)p.x; b += (double)p.y;
        c += (double)p.z; d += (double)p.w;
    }
    for (int off = 32; off > 0; off >>= 1) {
        a += __shfl_down(a, off, 64);
        b += __shfl_down(b, off, 64);
        c += __shfl_down(c, off, 64);
        d += __shfl_down(d, off, 64);
    }
    __shared__ double red[4][4];
    const int lane = threadIdx.x & 63;
    const int wid  = threadIdx.x >> 6;
    if (lane == 0) {
        red[wid][0] = a; red[wid][1] = b; red[wid][2] = c; red[wid][3] = d;
    }
    __syncthreads();
    if (threadIdx.x == 0) {
        double sa = 0, sb = 0, sc = 0, sd = 0;
        for (int w = 0; w < 4; ++w) {
            sa += red[w][0]; sb += red[w][1];
            sc += red[w][2]; sd += red[w][3];
        }
        const double n  = (double)N;
        const double vx = (sb - sa*sa/n) / (n - 1.0);
        const double vy = (sd - sc*sc/n) / (n - 1.0);
        const double dx = sqrt(vx) - SIGMA_T;
        const double dy = sqrt(vy) - SIGMA_T;
        out[0] = (float)sqrt(dx*dx + dy*dy);
    }
}

extern "C" void kernel_launch(void* const* d_in, const int* in_sizes, int n_in,
                              void* d_out, int out_size, void* d_ws, size_t ws_size,
                              hipStream_t stream) {
    const float* xs  = (const float*)d_in[0];
    const float* pxs = (const float*)d_in[1];
    const float* ys  = (const float*)d_in[2];
    const float* pys = (const float*)d_in[3];
    // d_in[4] = z : dead
    const float* pzs = (const float*)d_in[5];
    const float* ks  = (const float*)d_in[6];
    // d_in[7] = n_slices : dead (exact slice composition)

    const int N = in_sizes[0];
    const int Q = in_sizes[6];

    float*  cf       = (float*)((char*)d_ws + 64);
    float4* partials = (float4*)((char*)d_ws + 4096);

    prep_kernel<<<1, 128, 0, stream>>>(ks, Q, cf);

    const int n4 = N >> 2;
    const int ntail = N & 3;
    int blocks = (n4 + 255) / 256;
    if (blocks < 1) blocks = 1;
    if (blocks > MAXBLK) blocks = MAXBLK;
    beam_kernel<<<blocks, 256, 0, stream>>>(xs, pxs, ys, pys, pzs, cf, n4, ntail, partials);
    finalize_kernel<<<1, 256, 0, stream>>>(partials, blocks, (float*)d_out, N);
}

// Round 8
// 22.348 us; speedup vs baseline: 3.2176x; 1.1056x over previous
//
#include <hip/hip_runtime.h>
#include <math.h>

// Beamline: D(0.45) [Q_c D(0.9)]x19 Q_19 D(0.45). Output = hypot(std(x)-s, std(y)-s).
// Only final x,y matter -> final px,py, z-channel, n_slices all dead.
//   x_f = m11(pz)*x0 + m12(pz)*px0  (exact chromatic linear map, deg-7 poly in pz)
//       + cubic(x0,px0,y0,py0)      (first-order drift-nonlinearity kicks, pz=0)
// Round-8: prep critical path parallelized. Chebyshev lattices = per-cell
// matrices on 256 threads + ordered 5-step shuffle tree product (was: 8 serial
// ~1300-f64-op chains, ~6.5us at ~5ns/dependent-op). Cubic prefixes = ordered
// Hillis-Steele matrix scan on wave 4. Formulas identical to R7 (absmax==0).
// Lessons kept: no contended atomics (R2), no dynamic-index arrays (R3), no
// per-block redundant prep (R5), no per-block device-scope fences (R6).

#define SIGMA_T 0.005
#define PZ_A 6.5e-3
#define NNODE 8
#define MAXQ 32
#define MAXBLK 2048

// cos(pi*(2i+1)/16), i = 0..7
#define T0  0.9807852804032304
#define T1  0.8314696123025452
#define T2  0.5555702330196022
#define T3  0.1950903220161283
#define T4 (-0.1950903220161283)
#define T5 (-0.5555702330196022)
#define T6 (-0.8314696123025452)
#define T7 (-0.9807852804032304)

struct M2 { double a11, a12, a21, a22; };

// quad 2x2 via signed-u series: u = A*L^2, C=sum u^k/(2k)!, S=sum u^k/(2k+1)!
// cos/cosh and sin/sinh unify; matches Bmad quad_mat2_calc to ~1e-17 for |u|<=0.05.
__device__ inline M2 quadmatS(double A, double rp, double irp, double L) {
    double u = A * L * L;
    double C = fma(u, fma(u, fma(u, fma(u, fma(u, fma(u, 1.0/479001600.0, 1.0/3628800.0),
                    1.0/40320.0), 1.0/720.0), 1.0/24.0), 0.5), 1.0);
    double S = fma(u, fma(u, fma(u, fma(u, fma(u, fma(u, 1.0/6227020800.0, 1.0/39916800.0),
                    1.0/362880.0), 1.0/5040.0), 1.0/120.0), 1.0/6.0), 1.0);
    M2 m;
    double LS = L * S;
    m.a11 = C;
    m.a12 = LS * irp;
    m.a21 = A * LS * rp;
    m.a22 = C;
    return m;
}
__device__ inline void lmul(M2& M, const M2& E) {  // M <- E*M
    double n11 = E.a11*M.a11 + E.a12*M.a21;
    double n12 = E.a11*M.a12 + E.a12*M.a22;
    double n21 = E.a21*M.a11 + E.a22*M.a21;
    double n22 = E.a21*M.a12 + E.a22*M.a22;
    M.a11=n11; M.a12=n12; M.a21=n21; M.a22=n22;
}
__device__ inline void ldrift(M2& M, double d) {   // M <- [[1,d],[0,1]]*M
    M.a11 += d * M.a21;
    M.a12 += d * M.a22;
}
__device__ inline M2 mmul(const M2& A, const M2& B) {  // A*B
    M2 r;
    r.a11 = A.a11*B.a11 + A.a12*B.a21;
    r.a12 = A.a11*B.a12 + A.a12*B.a22;
    r.a21 = A.a21*B.a11 + A.a22*B.a21;
    r.a22 = A.a21*B.a12 + A.a22*B.a22;
    return r;
}
__device__ inline M2 shfl_down_m2(const M2& m, int d, int w) {
    M2 r;
    r.a11 = __shfl_down(m.a11, d, w);
    r.a12 = __shfl_down(m.a12, d, w);
    r.a21 = __shfl_down(m.a21, d, w);
    r.a22 = __shfl_down(m.a22, d, w);
    return r;
}
__device__ inline M2 shfl_up_m2(const M2& m, int d, int w) {
    M2 r;
    r.a11 = __shfl_up(m.a11, d, w);
    r.a12 = __shfl_up(m.a12, d, w);
    r.a21 = __shfl_up(m.a21, d, w);
    r.a22 = __shfl_up(m.a22, d, w);
    return r;
}

__device__ inline float uniflds(const float* p) {
    return __int_as_float(__builtin_amdgcn_readfirstlane(__float_as_int(*p)));
}

// cf layout (floats at d_ws+64):
//  [0..31]  horner: f*8+k, f in {mx11,mx12,my11,my12}, ascending power of t=pz/PZ_A
//  [32..41] Cx[10]: dx = x(C0 xx+C1 xp+C2 pp+C4 yy+C5 yq+C6 qq) + p(C3 pp+C7 yy+C8 yq+C9 qq)
//  [42..51] Cy[10]: symmetric
// prep: 320 threads. Waves 0-3: 8 nodes x 32 cell-slots, tree product.
//       Wave 4: cubic coeffs via prefix matrix scan over drifts.
__global__ __launch_bounds__(320) void prep_kernel(
    const float* __restrict__ ks, int Q, float* __restrict__ cf)
{
    __shared__ double Mn[NNODE][4];
    __shared__ float klds[64];
    const int tid = threadIdx.x;
    if (Q > MAXQ) Q = MAXQ;

    if (tid < 64) klds[tid] = (tid < Q) ? ks[tid] : 0.0f;
    __syncthreads();

    if (tid < 256) {
        // ---- Chebyshev nodes: lane = node*32 + cell ----
        const int cell = tid & 31;
        const int node = tid >> 5;
        const double TNv[NNODE] = {T0, T1, T2, T3, T4, T5, T6, T7};
        double t = TNv[node];                 // node uniform within 32-group ->
                                              // effectively scalar-indexed
        double pz = PZ_A * t;
        double rp = 1.0 + pz;
        double irp = 1.0 / rp;
        M2 X{1,0,0,1}, Y{1,0,0,1};
        if (cell < Q) {
            // C_cell = D(d_cell)*Q_cell, with D(0.45) folded into cell 0
            if (cell == 0) { ldrift(X, 0.45*irp); ldrift(Y, 0.45*irp); }
            double k1n = (double)klds[cell] * irp;
            lmul(X, quadmatS(-k1n, rp, irp, 0.1));
            lmul(Y, quadmatS( k1n, rp, irp, 0.1));
            double d = ((cell == Q-1) ? 0.45 : 0.9) * irp;
            ldrift(X, d); ldrift(Y, d);
        }
        // ordered tree product within 32-lane group: P_j <- P_{j+2^s} * P_j.
        // Lane 0's dependency tree only consumes in-range lanes; idle cells
        // hold identity.
        #pragma unroll
        for (int s = 0; s < 5; ++s) {
            M2 TX = shfl_down_m2(X, 1 << s, 32);
            M2 TY = shfl_down_m2(Y, 1 << s, 32);
            X = mmul(TX, X);
            Y = mmul(TY, Y);
        }
        if (cell == 0) {
            Mn[node][0]=X.a11; Mn[node][1]=X.a12; Mn[node][2]=Y.a11; Mn[node][3]=Y.a12;
        }
    } else {
        // ---- wave 4: cubic drift-kick coeffs at pz=0 via prefix scan ----
        // Sequence: D_0(0.45) Q_0 D_1(0.9) Q_1 ... Q_{Q-1} D_Q(0.45).
        // H_j = Q_{j-1} * D_{j-1}  (j=1..Q), H_0 = I.
        // Inclusive scan P_j = H_j*...*H_0 = snapshot at start of drift j.
        const int lane = tid - 256;           // 0..63
        M2 X{1,0,0,1}, Y{1,0,0,1};
        if (lane >= 1 && lane <= Q) {
            double Lprev = (lane == 1) ? 0.45 : 0.9;   // length of D_{lane-1}
            ldrift(X, Lprev); ldrift(Y, Lprev);
            double k1 = (double)klds[lane-1];
            lmul(X, quadmatS(-k1, 1.0, 1.0, 0.1));
            lmul(Y, quadmatS( k1, 1.0, 1.0, 0.1));
        }
        #pragma unroll
        for (int s = 0; s < 5; ++s) {
            M2 TX = shfl_up_m2(X, 1 << s, 64);
            M2 TY = shfl_up_m2(Y, 1 << s, 64);
            if (lane >= (1 << s)) { X = mmul(X, TX); Y = mmul(Y, TY); }
        }
        // Mtot = D(0.45) * P_Q   (broadcast P_Q from lane Q)
        M2 MX, MY;
        MX.a11 = __shfl(X.a11, Q, 64); MX.a12 = __shfl(X.a12, Q, 64);
        MX.a21 = __shfl(X.a21, Q, 64); MX.a22 = __shfl(X.a22, Q, 64);
        MY.a11 = __shfl(Y.a11, Q, 64); MY.a12 = __shfl(Y.a12, Q, 64);
        MY.a21 = __shfl(Y.a21, Q, 64); MY.a22 = __shfl(Y.a22, Q, 64);
        ldrift(MX, 0.45); ldrift(MY, 0.45);

        // kick at end of drift j (= lane): du = L*pu*(pu^2+pv^2)/2,
        // pu = a*x0 + b*px0 with (a,b) = P_j's (a21,a22); propagated by
        // R = Mtot.a11*b - Mtot.a12*a (det=1; drift-invariant).
        double con[20];
        #pragma unroll
        for (int v = 0; v < 20; ++v) con[v] = 0.0;
        if (lane <= Q) {
            double Lj = (lane == 0 || lane == Q) ? 0.45 : 0.9;
            double a = X.a21, b = X.a22, c2 = Y.a21, d2 = Y.a22;
            double Rx = MX.a11*b - MX.a12*a;
            double Ry = MY.a11*d2 - MY.a12*c2;
            double g = 0.5 * Lj * Rx;
            double h = 0.5 * Lj * Ry;
            con[0]=g*a*a*a;   con[1]=3.0*g*a*a*b;  con[2]=3.0*g*a*b*b;  con[3]=g*b*b*b;
            con[4]=g*a*c2*c2; con[5]=2.0*g*a*c2*d2; con[6]=g*a*d2*d2;
            con[7]=g*b*c2*c2; con[8]=2.0*g*b*c2*d2; con[9]=g*b*d2*d2;
            con[10]=h*c2*c2*c2; con[11]=3.0*h*c2*c2*d2; con[12]=3.0*h*c2*d2*d2; con[13]=h*d2*d2*d2;
            con[14]=h*c2*a*a;  con[15]=2.0*h*c2*a*b; con[16]=h*c2*b*b;
            con[17]=h*d2*a*a;  con[18]=2.0*h*d2*a*b; con[19]=h*d2*b*b;
        }
        #pragma unroll
        for (int v = 0; v < 20; ++v) {
            #pragma unroll
            for (int off = 32; off > 0; off >>= 1)
                con[v] += __shfl_down(con[v], off, 64);
        }
        if (lane == 0) {
            #pragma unroll
            for (int v = 0; v < 10; ++v) { cf[32+v]=(float)con[v]; cf[42+v]=(float)con[10+v]; }
        }
    }
    __syncthreads();

    if (tid < 4) {
        // Newton divided differences, fully unrolled (registers only).
        // Constant divisors written as reciprocal multiplies.
        constexpr double TN[NNODE] = {T0, T1, T2, T3, T4, T5, T6, T7};
        double d[NNODE];
        #pragma unroll
        for (int m = 0; m < NNODE; ++m) d[m] = Mn[m][tid];
        #pragma unroll
        for (int k = 1; k < NNODE; ++k) {
            #pragma unroll
            for (int m = NNODE - 1; m >= 1; --m) {
                if (m >= k) d[m] = (d[m] - d[m-1]) * (1.0 / (TN[m] - TN[m-k]));
            }
        }
        double c[NNODE];
        c[0] = d[NNODE-1];
        #pragma unroll
        for (int k = 1; k < NNODE; ++k) c[k] = 0.0;
        #pragma unroll
        for (int m = NNODE - 2; m >= 0; --m) {
            #pragma unroll
            for (int k = NNODE - 1; k >= 1; --k) c[k] = c[k-1] - TN[m]*c[k];
            c[0] = d[m] - TN[m]*c[0];
        }
        #pragma unroll
        for (int k = 0; k < NNODE; ++k) cf[tid*8 + k] = (float)c[k];
    }
}

__global__ __launch_bounds__(256) void beam_kernel(
    const float* __restrict__ xs, const float* __restrict__ pxs,
    const float* __restrict__ ys, const float* __restrict__ pys,
    const float* __restrict__ pzs, const float* __restrict__ cf,
    int n4, int ntail, float4* __restrict__ partials)
{
    float h[32], Cx[10], Cy[10];
    #pragma unroll
    for (int k = 0; k < 32; ++k) h[k] = uniflds(cf + k);
    #pragma unroll
    for (int k = 0; k < 10; ++k) { Cx[k] = uniflds(cf + 32 + k); Cy[k] = uniflds(cf + 42 + k); }

    const float inva = (float)(1.0 / PZ_A);
    float s1x = 0.f, s2x = 0.f, s1y = 0.f, s2y = 0.f;

    auto track = [&](float x, float p, float y, float q, float pz) {
        float t = pz * inva;
        float m11 = h[7], m12 = h[15], n11 = h[23], n12 = h[31];
        #pragma unroll
        for (int k = 6; k >= 0; --k) {
            m11 = fmaf(m11, t, h[k]);
            m12 = fmaf(m12, t, h[8+k]);
            n11 = fmaf(n11, t, h[16+k]);
            n12 = fmaf(n12, t, h[24+k]);
        }
        float xx = x*x, xp = x*p, pp = p*p;
        float yy = y*y, yq = y*q, qq = q*q;
        float A1 = Cx[0]*xx; A1=fmaf(Cx[1],xp,A1); A1=fmaf(Cx[2],pp,A1);
        A1=fmaf(Cx[4],yy,A1); A1=fmaf(Cx[5],yq,A1); A1=fmaf(Cx[6],qq,A1);
        float A2 = Cx[3]*pp; A2=fmaf(Cx[7],yy,A2); A2=fmaf(Cx[8],yq,A2); A2=fmaf(Cx[9],qq,A2);
        float B1 = Cy[0]*yy; B1=fmaf(Cy[1],yq,B1); B1=fmaf(Cy[2],qq,B1);
        B1=fmaf(Cy[4],xx,B1); B1=fmaf(Cy[5],xp,B1); B1=fmaf(Cy[6],pp,B1);
        float B2 = Cy[3]*qq; B2=fmaf(Cy[7],xx,B2); B2=fmaf(Cy[8],xp,B2); B2=fmaf(Cy[9],pp,B2);
        float xf = fmaf(m11, x, m12*p); xf = fmaf(x, A1, xf); xf = fmaf(p, A2, xf);
        float yf = fmaf(n11, y, n12*q); yf = fmaf(y, B1, yf); yf = fmaf(q, B2, yf);
        s1x += xf; s2x = fmaf(xf, xf, s2x);
        s1y += yf; s2y = fmaf(yf, yf, s2y);
    };

    const int gstride = gridDim.x * blockDim.x;
    for (int i = blockIdx.x * blockDim.x + threadIdx.x; i < n4; i += gstride) {
        float4 xv  = ((const float4*)xs)[i];
        float4 pxv = ((const float4*)pxs)[i];
        float4 yv  = ((const float4*)ys)[i];
        float4 pyv = ((const float4*)pys)[i];
        float4 pzv = ((const float4*)pzs)[i];
        track(xv.x, pxv.x, yv.x, pyv.x, pzv.x);
        track(xv.y, pxv.y, yv.y, pyv.y, pzv.y);
        track(xv.z, pxv.z, yv.z, pyv.z, pzv.z);
        track(xv.w, pxv.w, yv.w, pyv.w, pzv.w);
    }
    if (blockIdx.x == 0 && threadIdx.x == 0) {
        for (int r = 0; r < ntail; ++r) {
            int idx = 4*n4 + r;
            track(xs[idx], pxs[idx], ys[idx], pys[idx], pzs[idx]);
        }
    }

    // wave shuffle reduce, then LDS across 4 waves
    for (int off = 32; off > 0; off >>= 1) {
        s1x += __shfl_down(s1x, off, 64);
        s2x += __shfl_down(s2x, off, 64);
        s1y += __shfl_down(s1y, off, 64);
        s2y += __shfl_down(s2y, off, 64);
    }
    __shared__ float red[4][4];
    const int lane = threadIdx.x & 63;
    const int wid  = threadIdx.x >> 6;
    if (lane == 0) {
        red[wid][0] = s1x; red[wid][1] = s2x;
        red[wid][2] = s1y; red[wid][3] = s2y;
    }
    __syncthreads();
    if (threadIdx.x == 0) {
        float a = 0.f, b = 0.f, c = 0.f, d = 0.f;
        const int nw = (blockDim.x + 63) >> 6;
        for (int w = 0; w < nw; ++w) {
            a += red[w][0]; b += red[w][1];
            c += red[w][2]; d += red[w][3];
        }
        partials[blockIdx.x] = make_float4(a, b, c, d);  // no atomics
    }
}

__global__ __launch_bounds__(256) void finalize_kernel(
    const float4* __restrict__ partials, int nparts,
    float* __restrict__ out, int N)
{
    double a = 0.0, b = 0.0, c = 0.0, d = 0.0;
    for (int i = threadIdx.x; i < nparts; i += 256) {
        float4 p = partials[i];
        a += (double)p.x; b += (double)p.y;
        c += (double)p.z; d += (double)p.w;
    }
    for (int off = 32; off > 0; off >>= 1) {
        a += __shfl_down(a, off, 64);
        b += __shfl_down(b, off, 64);
        c += __shfl_down(c, off, 64);
        d += __shfl_down(d, off, 64);
    }
    __shared__ double red[4][4];
    const int lane = threadIdx.x & 63;
    const int wid  = threadIdx.x >> 6;
    if (lane == 0) {
        red[wid][0] = a; red[wid][1] = b; red[wid][2] = c; red[wid][3] = d;
    }
    __syncthreads();
    if (threadIdx.x == 0) {
        double sa = 0, sb = 0, sc = 0, sd = 0;
        for (int w = 0; w < 4; ++w) {
            sa += red[w][0]; sb += red[w][1];
            sc += red[w][2]; sd += red[w][3];
        }
        const double n  = (double)N;
        const double vx = (sb - sa*sa/n) / (n - 1.0);
        const double vy = (sd - sc*sc/n) / (n - 1.0);
        const double dx = sqrt(vx) - SIGMA_T;
        const double dy = sqrt(vy) - SIGMA_T;
        out[0] = (float)sqrt(dx*dx + dy*dy);
    }
}

extern "C" void kernel_launch(void* const* d_in, const int* in_sizes, int n_in,
                              void* d_out, int out_size, void* d_ws, size_t ws_size,
                              hipStream_t stream) {
    const float* xs  = (const float*)d_in[0];
    const float* pxs = (const float*)d_in[1];
    const float* ys  = (const float*)d_in[2];
    const float* pys = (const float*)d_in[3];
    // d_in[4] = z : dead
    const float* pzs = (const float*)d_in[5];
    const float* ks  = (const float*)d_in[6];
    // d_in[7] = n_slices : dead (exact slice composition)

    const int N = in_sizes[0];
    const int Q = in_sizes[6];

    float*  cf       = (float*)((char*)d_ws + 64);
    float4* partials = (float4*)((char*)d_ws + 4096);

    prep_kernel<<<1, 320, 0, stream>>>(ks, Q, cf);

    const int n4 = N >> 2;
    const int ntail = N & 3;
    int blocks = (n4 + 255) / 256;
    if (blocks < 1) blocks = 1;
    if (blocks > MAXBLK) blocks = MAXBLK;
    beam_kernel<<<blocks, 256, 0, stream>>>(xs, pxs, ys, pys, pzs, cf, n4, ntail, partials);
    finalize_kernel<<<1, 256, 0, stream>>>(partials, blocks, (float*)d_out, N);
}